// Round 3
// baseline (73.253 us; speedup 1.0000x reference)
//
#include <hip/hip_runtime.h>
#include <cmath>

#define BB 4
#define TT 8192
#define DD 1024
#define CL 64           // chunk length along T
#define NC 128          // TT / CL chunks

typedef float fvec4 __attribute__((ext_vector_type(4)));
typedef float fvec2 __attribute__((ext_vector_type(2)));

// y[b,t,d] = sum_{s<=t} x[b,s,d] * exp(-|decay_d|*(t-s)) * cos(freq_d*(t-s))
//          = Re(h[t]),  h[t] = r*h[t-1] + x[t],  r = exp(-|a|)*(cos w + i sin w)
//
// 3 passes: (1) per-chunk local scan -> chunk-final complex carry
//           (2) wave-parallel scan of carries per (b,d) -> exclusive incoming state
//           (3) rescan chunks seeded with incoming state, write y = Re(h)

// ---------- pass 1: per-chunk local scan, emit chunk-final complex state ----------
__global__ __launch_bounds__(256) void fftconv_pass1(
    const float* __restrict__ x, const float* __restrict__ decay,
    const float* __restrict__ freq, float2* __restrict__ carry)
{
    int g = blockIdx.x * 256 + threadIdx.x;      // B * NC * (D/4) threads
    int dq   = g & (DD / 4 - 1);                 // d-quad index
    int rest = g >> 8;
    int c = rest & (NC - 1);
    int b = rest >> 7;
    int d0 = dq << 2;

    fvec4 dc = *reinterpret_cast<const fvec4*>(decay + d0);
    fvec4 fq = *reinterpret_cast<const fvec4*>(freq + d0);
    float s, cc, e;
    e = expf(-fabsf(dc.x)); sincosf(fq.x, &s, &cc); float r0r = e*cc, r0i = e*s;
    e = expf(-fabsf(dc.y)); sincosf(fq.y, &s, &cc); float r1r = e*cc, r1i = e*s;
    e = expf(-fabsf(dc.z)); sincosf(fq.z, &s, &cc); float r2r = e*cc, r2i = e*s;
    e = expf(-fabsf(dc.w)); sincosf(fq.w, &s, &cc); float r3r = e*cc, r3i = e*s;

    const float* xp = x + ((size_t)(b * TT + c * CL)) * DD + d0;
    float h0r=0.f,h0i=0.f,h1r=0.f,h1i=0.f,h2r=0.f,h2i=0.f,h3r=0.f,h3i=0.f;
#pragma unroll 8
    for (int i = 0; i < CL; ++i) {
        fvec4 xv = *reinterpret_cast<const fvec4*>(xp);
        xp += DD;
        float t0 = fmaf(r0r,h0r, fmaf(-r0i,h0i, xv.x)); h0i = fmaf(r0r,h0i, r0i*h0r); h0r = t0;
        float t1 = fmaf(r1r,h1r, fmaf(-r1i,h1i, xv.y)); h1i = fmaf(r1r,h1i, r1i*h1r); h1r = t1;
        float t2 = fmaf(r2r,h2r, fmaf(-r2i,h2i, xv.z)); h2i = fmaf(r2r,h2i, r2i*h2r); h2r = t2;
        float t3 = fmaf(r3r,h3r, fmaf(-r3i,h3i, xv.w)); h3i = fmaf(r3r,h3i, r3i*h3r); h3r = t3;
    }
    size_t base = ((size_t)(b * NC + c)) * DD + d0;   // float2 index
    fvec4 o0 = {h0r,h0i,h1r,h1i};
    fvec4 o1 = {h2r,h2i,h3r,h3i};
    *reinterpret_cast<fvec4*>(&carry[base])     = o0;
    *reinterpret_cast<fvec4*>(&carry[base + 2]) = o1;
}

// ---------- pass 2: wave-parallel scan of chunk carries per (b, d-pair) ----------
// One 64-lane wave owns one (b, d-pair) sequence of NC=128 carries (2 per lane).
// Hillis-Steele inclusive scan over 64 pair-values with multiplier (R^{2L})^o,
// powers generated by repeated squaring. Slots overwritten with EXCLUSIVE
// incoming state for each chunk.
__global__ __launch_bounds__(256) void fftconv_pass2(
    const float* __restrict__ decay, const float* __restrict__ freq,
    float2* __restrict__ carry)
{
    int tid  = blockIdx.x * 256 + threadIdx.x;   // B * (D/2) * 64 threads
    int lane = threadIdx.x & 63;
    int w    = tid >> 6;                         // wave id: B * D/2
    int dp   = w & (DD / 2 - 1);
    int b    = w >> 9;
    int d0   = dp << 1;

    fvec2 dc = *reinterpret_cast<const fvec2*>(decay + d0);
    fvec2 fq = *reinterpret_cast<const fvec2*>(freq + d0);
    float s, cc, e;
    // M = R^CL per d
    e = expf(-fabsf(dc.x) * (float)CL); sincosf(fq.x * (float)CL, &s, &cc);
    float M0r = e*cc, M0i = e*s;
    e = expf(-fabsf(dc.y) * (float)CL); sincosf(fq.y * (float)CL, &s, &cc);
    float M1r = e*cc, M1i = e*s;

    // load the two chunk carries owned by this lane
    size_t base0 = ((size_t)(b * NC + 2 * lane)) * DD + d0;      // float2 idx
    fvec4 v0 = *reinterpret_cast<const fvec4*>(&carry[base0]);          // chunk 2l
    fvec4 v1 = *reinterpret_cast<const fvec4*>(&carry[base0 + DD]);     // chunk 2l+1

    // pair value p = M*v0 + v1 (per d, complex)
    float p0r = fmaf(M0r,v0.x, fmaf(-M0i,v0.y, v1.x));
    float p0i = fmaf(M0r,v0.y, fmaf( M0i,v0.x, v1.y));
    float p1r = fmaf(M1r,v0.z, fmaf(-M1i,v0.w, v1.z));
    float p1i = fmaf(M1r,v0.w, fmaf( M1i,v0.z, v1.w));

    // scan multiplier starts at M^2 = R^{2L}; squared each step
    float Q0r = fmaf(M0r,M0r, -M0i*M0i), Q0i = 2.f*M0r*M0i;
    float Q1r = fmaf(M1r,M1r, -M1i*M1i), Q1i = 2.f*M1r*M1i;

#pragma unroll
    for (int o = 1; o < 64; o <<= 1) {
        float u0r = __shfl_up(p0r, o, 64);
        float u0i = __shfl_up(p0i, o, 64);
        float u1r = __shfl_up(p1r, o, 64);
        float u1i = __shfl_up(p1i, o, 64);
        if (lane >= o) {
            float n0r = fmaf(Q0r,u0r, fmaf(-Q0i,u0i, p0r));
            p0i = fmaf(Q0r,u0i, fmaf( Q0i,u0r, p0i)); p0r = n0r;
            float n1r = fmaf(Q1r,u1r, fmaf(-Q1i,u1i, p1r));
            p1i = fmaf(Q1r,u1i, fmaf( Q1i,u1r, p1i)); p1r = n1r;
        }
        // square the multiplier for next offset
        float q0r = fmaf(Q0r,Q0r, -Q0i*Q0i); Q0i = 2.f*Q0r*Q0i; Q0r = q0r;
        float q1r = fmaf(Q1r,Q1r, -Q1i*Q1i); Q1i = 2.f*Q1r*Q1i; Q1r = q1r;
    }

    // exclusive: E_l = P_{l-1} (inclusive through chunk 2l-1), lane 0 -> 0
    float E0r = __shfl_up(p0r, 1, 64);
    float E0i = __shfl_up(p0i, 1, 64);
    float E1r = __shfl_up(p1r, 1, 64);
    float E1i = __shfl_up(p1i, 1, 64);
    if (lane == 0) { E0r=0.f; E0i=0.f; E1r=0.f; E1i=0.f; }

    // incoming for chunk 2l   = E
    // incoming for chunk 2l+1 = M*E + v0
    float F0r = fmaf(M0r,E0r, fmaf(-M0i,E0i, v0.x));
    float F0i = fmaf(M0r,E0i, fmaf( M0i,E0r, v0.y));
    float F1r = fmaf(M1r,E1r, fmaf(-M1i,E1i, v0.z));
    float F1i = fmaf(M1r,E1i, fmaf( M1i,E1r, v0.w));

    fvec4 e0 = {E0r,E0i,E1r,E1i};
    fvec4 f0 = {F0r,F0i,F1r,F1i};
    *reinterpret_cast<fvec4*>(&carry[base0])      = e0;
    *reinterpret_cast<fvec4*>(&carry[base0 + DD]) = f0;
}

// ---------- pass 3: rescan chunks seeded with incoming carry, write y = Re(h) ----------
__global__ __launch_bounds__(256) void fftconv_pass3(
    const float* __restrict__ x, const float* __restrict__ decay,
    const float* __restrict__ freq, const float2* __restrict__ carry,
    float* __restrict__ y)
{
    int g = blockIdx.x * 256 + threadIdx.x;      // B * NC * (D/4) threads
    int dq   = g & (DD / 4 - 1);
    int rest = g >> 8;
    int c = rest & (NC - 1);
    int b = rest >> 7;
    int d0 = dq << 2;

    fvec4 dc = *reinterpret_cast<const fvec4*>(decay + d0);
    fvec4 fq = *reinterpret_cast<const fvec4*>(freq + d0);
    float s, cc, e;
    e = expf(-fabsf(dc.x)); sincosf(fq.x, &s, &cc); float r0r = e*cc, r0i = e*s;
    e = expf(-fabsf(dc.y)); sincosf(fq.y, &s, &cc); float r1r = e*cc, r1i = e*s;
    e = expf(-fabsf(dc.z)); sincosf(fq.z, &s, &cc); float r2r = e*cc, r2i = e*s;
    e = expf(-fabsf(dc.w)); sincosf(fq.w, &s, &cc); float r3r = e*cc, r3i = e*s;

    size_t base = ((size_t)(b * NC + c)) * DD + d0;
    fvec4 c01 = *reinterpret_cast<const fvec4*>(&carry[base]);
    fvec4 c23 = *reinterpret_cast<const fvec4*>(&carry[base + 2]);
    float h0r=c01.x,h0i=c01.y,h1r=c01.z,h1i=c01.w;
    float h2r=c23.x,h2i=c23.y,h3r=c23.z,h3i=c23.w;

    size_t off = ((size_t)(b * TT + c * CL)) * DD + d0;
    const float* xp = x + off;
    float*       yp = y + off;
#pragma unroll 8
    for (int i = 0; i < CL; ++i) {
        fvec4 xv = *reinterpret_cast<const fvec4*>(xp);
        xp += DD;
        float t0 = fmaf(r0r,h0r, fmaf(-r0i,h0i, xv.x)); h0i = fmaf(r0r,h0i, r0i*h0r); h0r = t0;
        float t1 = fmaf(r1r,h1r, fmaf(-r1i,h1i, xv.y)); h1i = fmaf(r1r,h1i, r1i*h1r); h1r = t1;
        float t2 = fmaf(r2r,h2r, fmaf(-r2i,h2i, xv.z)); h2i = fmaf(r2r,h2i, r2i*h2r); h2r = t2;
        float t3 = fmaf(r3r,h3r, fmaf(-r3i,h3i, xv.w)); h3i = fmaf(r3r,h3i, r3i*h3r); h3r = t3;
        // nontemporal: keep y out of L3 so x stays resident for this pass
        fvec4 yv = {h0r,h1r,h2r,h3r};
        __builtin_nontemporal_store(yv, reinterpret_cast<fvec4*>(yp));
        yp += DD;
    }
}

extern "C" void kernel_launch(void* const* d_in, const int* in_sizes, int n_in,
                              void* d_out, int out_size, void* d_ws, size_t ws_size,
                              hipStream_t stream) {
    const float* x     = (const float*)d_in[0];
    const float* decay = (const float*)d_in[1];
    const float* freq  = (const float*)d_in[2];
    float*       y     = (float*)d_out;
    float2*      carry = (float2*)d_ws;          // B*NC*D float2 = 4 MB

    const int thr13 = BB * NC * (DD / 4);        // 131072
    const int thr2  = BB * (DD / 2) * 64;        // 131072 (one wave per (b,dpair))
    fftconv_pass1<<<thr13 / 256, 256, 0, stream>>>(x, decay, freq, carry);
    fftconv_pass2<<<thr2  / 256, 256, 0, stream>>>(decay, freq, carry);
    fftconv_pass3<<<thr13 / 256, 256, 0, stream>>>(x, decay, freq, carry, y);
}